// Round 2
// baseline (662.962 us; speedup 1.0000x reference)
//
#include <hip/hip_runtime.h>
#include <math.h>

// Shapes
#define B_   128
#define D_   1024
#define H_   256
#define M_   100
#define K_   5
#define MD   102400   // M_*D_
#define EPS_ 1e-5f

// d_out layout (f32): probs[128*100*1024], scores[12800], syn[12800], logits[128*100*1024]
#define OFF_SCORES 13107200
#define OFF_SYN    13120000
#define OFF_LOGITS 13132800

// ---------------- reduction helpers (block-wide, used by gen kernel only) ----------
__device__ __forceinline__ void block_sum2(float& a, float& b, float* red, int t) {
  #pragma unroll
  for (int off = 1; off < 64; off <<= 1) { a += __shfl_xor(a, off); b += __shfl_xor(b, off); }
  if ((t & 63) == 0) { red[(t >> 6) * 2] = a; red[(t >> 6) * 2 + 1] = b; }
  __syncthreads();
  a = red[0] + red[2] + red[4] + red[6];
  b = red[1] + red[3] + red[5] + red[7];
  __syncthreads();
}

// ---------------- K1: generator layers 1+2 (per batch row) ----------------
// Writes h2 TRANSPOSED: h2t[k*128 + b]  (so gemm3 A-frags are contiguous float4s)
__global__ __launch_bounds__(256) void gen_mlp_kernel(
    const float* __restrict__ x,
    const float* __restrict__ gW1, const float* __restrict__ gb1,
    const float* __restrict__ ln1s, const float* __restrict__ ln1b,
    const float* __restrict__ gW2, const float* __restrict__ gb2,
    const float* __restrict__ ln2s, const float* __restrict__ ln2b,
    float* __restrict__ h2t)
{
  __shared__ float xs[1024];
  __shared__ float h1s[512];
  __shared__ float red[8];
  int b = blockIdx.x, t = threadIdx.x;
  const float* xr = x + b * 1024;
  #pragma unroll
  for (int i = 0; i < 4; ++i) xs[t + i * 256] = xr[t + i * 256];
  __syncthreads();

  // layer1: thread computes outputs o=2t, 2t+1 (512 outputs)
  float a0 = 0.f, a1 = 0.f;
  #pragma unroll 4
  for (int d = 0; d < 1024; ++d) {
    float xv = xs[d];
    float2 w = *(const float2*)&gW1[d * 512 + 2 * t];
    a0 = fmaf(xv, w.x, a0);
    a1 = fmaf(xv, w.y, a1);
  }
  a0 += gb1[2 * t]; a1 += gb1[2 * t + 1];
  float s = a0 + a1, sq = a0 * a0 + a1 * a1;
  block_sum2(s, sq, red, t);
  float mu = s * (1.f / 512.f);
  float var = sq * (1.f / 512.f) - mu * mu;
  float inv = rsqrtf(var + EPS_);
  h1s[2 * t]     = fmaxf((a0 - mu) * inv * ln1s[2 * t]     + ln1b[2 * t],     0.f);
  h1s[2 * t + 1] = fmaxf((a1 - mu) * inv * ln1s[2 * t + 1] + ln1b[2 * t + 1], 0.f);
  __syncthreads();

  // layer2: thread computes output o=t (256 outputs)
  float acc = 0.f;
  #pragma unroll 4
  for (int h = 0; h < 512; ++h) acc = fmaf(h1s[h], gW2[h * 256 + t], acc);
  acc += gb2[t];
  float s2 = acc, sq2 = acc * acc;
  block_sum2(s2, sq2, red, t);
  float mu2 = s2 * (1.f / 256.f);
  float var2 = sq2 * (1.f / 256.f) - mu2 * mu2;
  float inv2 = rsqrtf(var2 + EPS_);
  h2t[t * 128 + b] = fmaxf((acc - mu2) * inv2 * ln2s[t] + ln2b[t], 0.f);
}

// ---------------- K2: logits = h2 @ gW3 + gb3  (128 x 102400, K=256) ----------------
// LDS-free, barrier-free. A (h2^T, 131 KB) is L2-resident & shared across all blocks.
// Block = 64 cols x 128 rows; thread = 8 rows x 4 cols. K unrolled x4: 12 loads
// issued per group before 128 FMAs -> deep VMEM pipelining, pure-FMA TLP across waves.
__global__ __launch_bounds__(256) void gemm3_kernel(
    const float* __restrict__ h2t, const float* __restrict__ gW3,
    const float* __restrict__ gb3, float* __restrict__ logits)
{
  int t = threadIdx.x;
  int col0 = blockIdx.x * 64;
  int c4 = (t & 15) * 4;
  int r8 = (t >> 4) * 8;
  int ra = r8 >> 2;
  const float4* W4 = (const float4*)(gW3 + col0 + c4);  // index: k * 25600
  const float4* A4 = (const float4*)h2t;                // index: k * 32 + ra

  float acc[8][4];
  #pragma unroll
  for (int i = 0; i < 8; ++i)
    #pragma unroll
    for (int j = 0; j < 4; ++j) acc[i][j] = 0.f;

  for (int k0 = 0; k0 < 256; k0 += 4) {
    float4 bq[4], x0[4], x1[4];
    #pragma unroll
    for (int u = 0; u < 4; ++u) bq[u] = W4[(k0 + u) * 25600];
    #pragma unroll
    for (int u = 0; u < 4; ++u) {
      x0[u] = A4[(k0 + u) * 32 + ra];
      x1[u] = A4[(k0 + u) * 32 + ra + 1];
    }
    #pragma unroll
    for (int u = 0; u < 4; ++u) {
      float a[8] = {x0[u].x, x0[u].y, x0[u].z, x0[u].w,
                    x1[u].x, x1[u].y, x1[u].z, x1[u].w};
      float bv[4] = {bq[u].x, bq[u].y, bq[u].z, bq[u].w};
      #pragma unroll
      for (int i = 0; i < 8; ++i)
        #pragma unroll
        for (int j = 0; j < 4; ++j) acc[i][j] = fmaf(a[i], bv[j], acc[i][j]);
    }
  }

  float4 bias = *(const float4*)&gb3[col0 + c4];
  #pragma unroll
  for (int i = 0; i < 8; ++i) {
    float4 o;
    o.x = acc[i][0] + bias.x; o.y = acc[i][1] + bias.y;
    o.z = acc[i][2] + bias.z; o.w = acc[i][3] + bias.w;
    *(float4*)&logits[(r8 + i) * MD + col0 + c4] = o;
  }
}

// ---------------- K3: softmax + top-5 + gathers + synergy + t1 ----------------
// ONE WAVE per (b,m) row: 64 lanes x 16 probs in registers. No LDS, no barriers.
// Argmax rounds use shfl_xor butterflies with (value desc, index asc) merge
// == jax.lax.top_k stable order.
__global__ __launch_bounds__(256) void tail_kernel(
    const float* __restrict__ x, const float* __restrict__ gumbel,
    const float* __restrict__ sW1, const float* __restrict__ sb1,
    const float* __restrict__ yW1, const float* __restrict__ yb1,
    const float* __restrict__ yW2, const float* __restrict__ yb2,
    const float* __restrict__ logits, float* __restrict__ probs,
    float* __restrict__ syn, float* __restrict__ t1ws)
{
  int t = threadIdx.x;
  int lane = t & 63;
  int row = blockIdx.x * 4 + (t >> 6);   // 3200 blocks x 4 waves
  int b = row / 100;

  const float4* lg4 = (const float4*)(logits + row * 1024);
  const float4* gm4 = (const float4*)(gumbel + row * 1024);

  // z = 2*(logit+gumbel); element d = i*256 + lane*4 + k lives in v[i*4+k]
  float v[16];
  float mx = -1e30f;
  #pragma unroll
  for (int i = 0; i < 4; ++i) {
    float4 L = lg4[i * 64 + lane];
    float4 G = gm4[i * 64 + lane];
    v[i * 4 + 0] = (L.x + G.x) * 2.f;
    v[i * 4 + 1] = (L.y + G.y) * 2.f;
    v[i * 4 + 2] = (L.z + G.z) * 2.f;
    v[i * 4 + 3] = (L.w + G.w) * 2.f;
    mx = fmaxf(mx, fmaxf(fmaxf(v[i*4], v[i*4+1]), fmaxf(v[i*4+2], v[i*4+3])));
  }
  #pragma unroll
  for (int off = 1; off < 64; off <<= 1) mx = fmaxf(mx, __shfl_xor(mx, off));

  float s = 0.f;
  #pragma unroll
  for (int r = 0; r < 16; ++r) { v[r] = expf(v[r] - mx); s += v[r]; }
  #pragma unroll
  for (int off = 1; off < 64; off <<= 1) s += __shfl_xor(s, off);
  float inv = 1.f / s;
  #pragma unroll
  for (int r = 0; r < 16; ++r) v[r] *= inv;

  float4* pr4 = (float4*)(probs + row * 1024);
  #pragma unroll
  for (int i = 0; i < 4; ++i)
    pr4[i * 64 + lane] = make_float4(v[i*4], v[i*4+1], v[i*4+2], v[i*4+3]);

  // t1/u1 accumulators: this lane owns output cols lane*4 .. lane*4+3
  const float4* sb1_4 = (const float4*)sb1;
  const float4* yb1_4 = (const float4*)yb1;
  const float4* sW1_4 = (const float4*)sW1;
  const float4* yW1_4 = (const float4*)yW1;
  float4 t1a = sb1_4[lane];
  float4 u1a = yb1_4[lane];

  const float* xb = x + b * 1024;
  #pragma unroll
  for (int sel = 0; sel < 5; ++sel) {
    // per-lane argmax (scan order = ascending d, strict > keeps lowest index)
    float bv = v[0];
    int bi = lane * 4;
    #pragma unroll
    for (int r = 1; r < 16; ++r) {
      int d = (r >> 2) * 256 + lane * 4 + (r & 3);
      if (v[r] > bv) { bv = v[r]; bi = d; }
    }
    // wave butterfly with (value desc, index asc) merge
    #pragma unroll
    for (int off = 1; off < 64; off <<= 1) {
      float ov = __shfl_xor(bv, off);
      int   oi = __shfl_xor(bi, off);
      if (ov > bv || (ov == bv && oi < bi)) { bv = ov; bi = oi; }
    }
    int w = bi;                       // uniform across wave
    // mask the selected element
    int wl = (w >> 2) & 63;
    int wr = ((w >> 8) << 2) | (w & 3);
    if (lane == wl) {
      #pragma unroll
      for (int r = 0; r < 16; ++r) if (r == wr) v[r] = -1.f;
    }
    float xv = xb[w];                 // broadcast load
    float4 sw = sW1_4[(sel * 1024 + w) * 64 + lane];
    float4 yw = yW1_4[(sel * 1024 + w) * 64 + lane];
    t1a.x = fmaf(xv, sw.x, t1a.x); t1a.y = fmaf(xv, sw.y, t1a.y);
    t1a.z = fmaf(xv, sw.z, t1a.z); t1a.w = fmaf(xv, sw.w, t1a.w);
    u1a.x = fmaf(xv, yw.x, u1a.x); u1a.y = fmaf(xv, yw.y, u1a.y);
    u1a.z = fmaf(xv, yw.z, u1a.z); u1a.w = fmaf(xv, yw.w, u1a.w);
  }

  float4 t1v = make_float4(fmaxf(t1a.x, 0.f), fmaxf(t1a.y, 0.f),
                           fmaxf(t1a.z, 0.f), fmaxf(t1a.w, 0.f));
  ((float4*)(t1ws + row * 256))[lane] = t1v;

  // synergy = tanh(relu(u1) . yW2 + yb2)
  float4 yw2 = ((const float4*)yW2)[lane];
  float part = fmaxf(u1a.x, 0.f) * yw2.x + fmaxf(u1a.y, 0.f) * yw2.y
             + fmaxf(u1a.z, 0.f) * yw2.z + fmaxf(u1a.w, 0.f) * yw2.w;
  #pragma unroll
  for (int off = 1; off < 64; off <<= 1) part += __shfl_xor(part, off);
  if (lane == 0) syn[row] = tanhf(part + yb2[0]);
}

// ---------------- K4: scores = sigmoid(relu(t1 @ sW2 + sb2) @ sW3 + sb3) ----------------
// Block = 64 rows x 128 cols, K=256; thread = 8 rows x 4 cols.
__global__ __launch_bounds__(256) void scorer2_kernel(
    const float* __restrict__ t1, const float* __restrict__ sW2,
    const float* __restrict__ sb2, const float* __restrict__ sW3,
    const float* __restrict__ sb3, float* __restrict__ scores)
{
  __shared__ float t1t[64 * 68];   // [kk][row], stride 68 (16B-aligned)
  __shared__ float red[64 * 32];
  int t = threadIdx.x;
  int row0 = blockIdx.x * 64;
  int c4 = (t & 31) * 4;
  int r8 = (t >> 5) * 8;
  float acc[8][4];
  #pragma unroll
  for (int i = 0; i < 8; ++i)
    #pragma unroll
    for (int j = 0; j < 4; ++j) acc[i][j] = 0.f;

  for (int c = 0; c < 4; ++c) {
    #pragma unroll
    for (int p = 0; p < 16; ++p) {
      int rr = p * 4 + (t >> 6);
      int kk = t & 63;
      t1t[kk * 68 + rr] = t1[(row0 + rr) * 256 + c * 64 + kk];
    }
    __syncthreads();
    #pragma unroll 4
    for (int kk = 0; kk < 64; ++kk) {
      float4 bf = *(const float4*)&sW2[(c * 64 + kk) * 128 + c4];
      float4 a0 = *(const float4*)&t1t[kk * 68 + r8];
      float4 a1 = *(const float4*)&t1t[kk * 68 + r8 + 4];
      float a[8] = {a0.x, a0.y, a0.z, a0.w, a1.x, a1.y, a1.z, a1.w};
      float bv[4] = {bf.x, bf.y, bf.z, bf.w};
      #pragma unroll
      for (int i = 0; i < 8; ++i)
        #pragma unroll
        for (int j = 0; j < 4; ++j) acc[i][j] = fmaf(a[i], bv[j], acc[i][j]);
    }
    __syncthreads();
  }

  float4 b2 = *(const float4*)&sb2[c4];
  float4 w3 = *(const float4*)&sW3[c4];
  #pragma unroll
  for (int i = 0; i < 8; ++i) {
    float s = fmaxf(acc[i][0] + b2.x, 0.f) * w3.x
            + fmaxf(acc[i][1] + b2.y, 0.f) * w3.y
            + fmaxf(acc[i][2] + b2.z, 0.f) * w3.z
            + fmaxf(acc[i][3] + b2.w, 0.f) * w3.w;
    red[(r8 + i) * 32 + (t & 31)] = s;
  }
  __syncthreads();
  if (t < 64) {
    float s = sb3[0];
    #pragma unroll
    for (int g = 0; g < 32; ++g) s += red[t * 32 + g];
    scores[row0 + t] = 1.f / (1.f + expf(-s));
  }
}

extern "C" void kernel_launch(void* const* d_in, const int* in_sizes, int n_in,
                              void* d_out, int out_size, void* d_ws, size_t ws_size,
                              hipStream_t stream) {
  const float* x    = (const float*)d_in[0];
  const float* gum  = (const float*)d_in[1];
  const float* gW1  = (const float*)d_in[2];
  const float* gb1  = (const float*)d_in[3];
  const float* ln1s = (const float*)d_in[4];
  const float* ln1b = (const float*)d_in[5];
  const float* gW2  = (const float*)d_in[6];
  const float* gb2  = (const float*)d_in[7];
  const float* ln2s = (const float*)d_in[8];
  const float* ln2b = (const float*)d_in[9];
  const float* gW3  = (const float*)d_in[10];
  const float* gb3  = (const float*)d_in[11];
  const float* sW1  = (const float*)d_in[12];
  const float* sb1  = (const float*)d_in[13];
  const float* sW2  = (const float*)d_in[14];
  const float* sb2  = (const float*)d_in[15];
  const float* sW3  = (const float*)d_in[16];
  const float* sb3  = (const float*)d_in[17];
  const float* yW1  = (const float*)d_in[18];
  const float* yb1  = (const float*)d_in[19];
  const float* yW2  = (const float*)d_in[20];
  const float* yb2  = (const float*)d_in[21];

  float* out    = (float*)d_out;
  float* probs  = out;
  float* scores = out + OFF_SCORES;
  float* syn    = out + OFF_SYN;
  float* logits = out + OFF_LOGITS;

  float* h2t = (float*)d_ws;                             // 256*128 f32 = 131 KB
  float* t1  = (float*)((char*)d_ws + 32768 * 4);        // 12800*256 f32 = 13.1 MB

  gen_mlp_kernel<<<128, 256, 0, stream>>>(x, gW1, gb1, ln1s, ln1b, gW2, gb2, ln2s, ln2b, h2t);
  gemm3_kernel<<<1600, 256, 0, stream>>>(h2t, gW3, gb3, logits);
  tail_kernel<<<3200, 256, 0, stream>>>(x, gum, sW1, sb1, yW1, yb1, yW2, yb2,
                                        logits, probs, syn, t1);
  scorer2_kernel<<<200, 256, 0, stream>>>(t1, sW2, sb2, sW3, sb3, scores);
}